// Round 2
// baseline (1225.272 us; speedup 1.0000x reference)
//
#include <hip/hip_runtime.h>
#include <hip/hip_bf16.h>
#include <cstdint>
#include <cstddef>

// ---------------------------------------------------------------------------
// RNNAttentionModel: embed -> 2-layer tanh RNN scan (8-wave, wave-specialized,
// the verified 561us structure) FUSED with transpose + (qproj + flash attn +
// FC) via role-split blocks + device-scope progress flags, so the post-scan
// work overlaps the scan on the 252 idle CUs.
// B=64 T=1024 E=64 H=128 V=55
// ---------------------------------------------------------------------------

typedef __attribute__((ext_vector_type(8))) short short8;
typedef __attribute__((ext_vector_type(4))) float f32x4;

__device__ __forceinline__ float bf2f(unsigned short u) {
    union { unsigned int i; float f; } c; c.i = ((unsigned int)u) << 16; return c.f;
}
__device__ __forceinline__ unsigned short f2bf(float f) {
    union { float f; unsigned int i; } c; c.f = f;
    unsigned int u = c.i;
    u += 0x7fffu + ((u >> 16) & 1u);   // RNE
    return (unsigned short)(u >> 16);
}
__device__ __forceinline__ unsigned int pk_bf16(float lo, float hi) {
    union { __hip_bfloat162 h2; unsigned int u; } c;
    c.h2 = __float22bfloat162_rn(make_float2(lo, hi));
    return c.u;
}
__device__ __forceinline__ float fast_tanh(float x) {
    float e = __expf(2.0f * x);
    return 1.0f - 2.0f * __builtin_amdgcn_rcpf(e + 1.0f);
}
__device__ __forceinline__ void bar_lds() {
    asm volatile("s_waitcnt lgkmcnt(0)\n\ts_barrier" ::: "memory");
}
__device__ __forceinline__ short8 ld_a_bf16(const float* p) {
    const float4* q = (const float4*)p;
    float4 f0 = q[0], f1 = q[1];
    short8 r;
    r[0]=(short)f2bf(f0.x); r[1]=(short)f2bf(f0.y);
    r[2]=(short)f2bf(f0.z); r[3]=(short)f2bf(f0.w);
    r[4]=(short)f2bf(f1.x); r[5]=(short)f2bf(f1.y);
    r[6]=(short)f2bf(f1.z); r[7]=(short)f2bf(f1.w);
    return r;
}
// split-precision load: hi = bf16(w), lo = bf16(w - hi); hi+lo ~ f32 weight
__device__ __forceinline__ void ld_fc_hilo(const float* p, short8& hi, short8& lo) {
    const float4* q = (const float4*)p;
    float4 f0 = q[0], f1 = q[1];
    float ff[8] = {f0.x, f0.y, f0.z, f0.w, f1.x, f1.y, f1.z, f1.w};
#pragma unroll
    for (int i = 0; i < 8; ++i) {
        unsigned short hb = f2bf(ff[i]);
        hi[i] = (short)hb;
        lo[i] = (short)f2bf(ff[i] - bf2f(hb));
    }
}
// ---- cross-XCD release/acquire (per-XCD L2s are not coherent) ----
__device__ __forceinline__ void rel_store(int* p, int v) {
    __threadfence();
    __hip_atomic_store(p, v, __ATOMIC_RELEASE, __HIP_MEMORY_SCOPE_AGENT);
}
__device__ __forceinline__ void acq_wait_ge(int* p, int v) {
    while (__hip_atomic_load(p, __ATOMIC_ACQUIRE, __HIP_MEMORY_SCOPE_AGENT) < v)
        __builtin_amdgcn_s_sleep(64);
}

// ---------------------------------------------------------------------------
// K0a: WE[v][i] = w_ih0[i,:] . emb[v,:] + b_ih0[i] + b_hh0[i]   (55 x 128)
// ---------------------------------------------------------------------------
__global__ __launch_bounds__(128)
void k_we(const float* __restrict__ emb, const float* __restrict__ w_ih0,
          const float* __restrict__ b_ih0, const float* __restrict__ b_hh0,
          float* __restrict__ WE)
{
    __shared__ float ev[64];
    const int i = threadIdx.x;
    const int v = blockIdx.x;
    if (i < 64) ev[i] = emb[v * 64 + i];
    __syncthreads();
    float s = b_ih0[i] + b_hh0[i];
    const float* wr = w_ih0 + i * 64;
#pragma unroll
    for (int k = 0; k < 64; ++k) s += wr[k] * ev[k];
    WE[v * 128 + i] = s;
}

// ---------------------------------------------------------------------------
// K0b: WEg[b][t][:] = WE[x[b][t]][:]
// ---------------------------------------------------------------------------
__global__ __launch_bounds__(256)
void k_weg(const int* __restrict__ x, const float* __restrict__ WE,
           float* __restrict__ WEg)
{
    __shared__ int xv[32];
    const int tid = threadIdx.x;
    const int b   = blockIdx.y;
    const int t0  = blockIdx.x * 32;
    if (tid < 32) xv[tid] = x[b * 1024 + t0 + tid];
    __syncthreads();
#pragma unroll
    for (int it = 0; it < 4; ++it) {
        int tt = it * 8 + (tid >> 5);
        int c4 = tid & 31;
        float4 v = ((const float4*)(WE + xv[tt] * 128))[c4];
        ((float4*)(WEg + ((size_t)b * 1024 + t0 + tt) * 128))[c4] = v;
    }
}

// ---------------------------------------------------------------------------
// flag zeroing (re-run safe; kernel boundary gives device-wide visibility)
// ---------------------------------------------------------------------------
__global__ __launch_bounds__(1024)
void k_zero(int* __restrict__ f)
{
    if (threadIdx.x < 544) f[threadIdx.x] = 0;
}

// ---------------------------------------------------------------------------
// Fused kernel. Roles by blockIdx.x:
//   [0,4)      : RNN scan (verified 8-wave k_scan5 math) + progress flags
//   [4,516)    : transpose chunk (chunk-major: i>>6 = chunk, i&63 = b)
//   [516,1028) : attn+FC (qt-ascending: i>>6 = qt, i&63 = b)
// Static LDS 100352B forces 1 block/CU -> scan CUs never shared.
// flags[0..3]   = scan progress (timesteps done) per scan block
// flags[16+b*8+c] = transpose chunk c of batch b done
// ---------------------------------------------------------------------------
__global__ __launch_bounds__(512, 1)
void k_fused(const float* __restrict__ WEg,
             const float* __restrict__ w_hh0,
             const float* __restrict__ w_ih1, const float* __restrict__ b_ih1,
             const float* __restrict__ w_hh1, const float* __restrict__ b_hh1,
             unsigned short* __restrict__ outs_bf,
             unsigned short* __restrict__ outsT,
             const float* __restrict__ attn_w, const float* __restrict__ attn_b,
             const float* __restrict__ fc_w, const float* __restrict__ fc_b,
             float* __restrict__ out, int* __restrict__ flags)
{
    __shared__ __align__(16) unsigned char smem[100352];
    const int bx   = blockIdx.x;
    const int tid  = threadIdx.x;
    const int w    = tid >> 6;
    const int lane = tid & 63;
    const int quad = lane >> 4;
    const int n    = lane & 15;

    if (bx < 4) {
        // =================== scan role (k_scan5, 8 waves) ===================
        typedef unsigned short (*HBuf)[16][136];
        HBuf h0buf = (HBuf)(smem);           // [2][16][136]
        HBuf h1buf = (HBuf)(smem + 8704);    // [2][16][136]
        const int bbase = bx * 16;

        if (w < 4) {
            const int r0 = w * 32 + quad * 4;
            const int r1 = r0 + 16;
            short8 a0[2][4];
#pragma unroll
            for (int r = 0; r < 2; ++r) {
                const size_t mrow = (size_t)(w * 32 + r * 16 + n) * 128;
#pragma unroll
                for (int ks = 0; ks < 4; ++ks)
                    a0[r][ks] = ld_a_bf16(w_hh0 + mrow + ks * 32 + quad * 8);
            }
            const size_t wegB0 = (size_t)(bbase + n) * 131072 + r0;
            const size_t wegB1 = wegB0 + 16;
            {
                float4 p0 = *(const float4*)(WEg + wegB0);
                float4 p1 = *(const float4*)(WEg + wegB1);
                *(uint2*)&h0buf[0][n][r0] = make_uint2(
                    pk_bf16(fast_tanh(p0.x), fast_tanh(p0.y)),
                    pk_bf16(fast_tanh(p0.z), fast_tanh(p0.w)));
                *(uint2*)&h0buf[0][n][r1] = make_uint2(
                    pk_bf16(fast_tanh(p1.x), fast_tanh(p1.y)),
                    pk_bf16(fast_tanh(p1.z), fast_tanh(p1.w)));
            }
            float4 wA0 = *(const float4*)(WEg + wegB0 + 128);
            float4 wA1 = *(const float4*)(WEg + wegB1 + 128);
            float4 wB0 = *(const float4*)(WEg + wegB0 + 256);
            float4 wB1 = *(const float4*)(WEg + wegB1 + 256);
            float4 wC0 = *(const float4*)(WEg + wegB0 + 384);
            float4 wC1 = *(const float4*)(WEg + wegB1 + 384);
            __syncthreads();

            for (int t = 0; t < 1024; ++t) {
                const int p = t & 1;
                if (t < 1023) {
                    const unsigned short* h0p = &h0buf[p][n][quad * 8];
                    short8 bh[4];
#pragma unroll
                    for (int ks = 0; ks < 4; ++ks)
                        bh[ks] = *(const short8*)(h0p + ks * 32);
                    f32x4 c0 = (f32x4){wA0.x, wA0.y, wA0.z, wA0.w};
                    f32x4 c1 = (f32x4){wA1.x, wA1.y, wA1.z, wA1.w};
#pragma unroll
                    for (int ks = 0; ks < 4; ++ks) {
                        c0 = __builtin_amdgcn_mfma_f32_16x16x32_bf16(a0[0][ks], bh[ks], c0, 0,0,0);
                        c1 = __builtin_amdgcn_mfma_f32_16x16x32_bf16(a0[1][ks], bh[ks], c1, 0,0,0);
                    }
                    wA0 = wB0; wA1 = wB1; wB0 = wC0; wB1 = wC1;
                    const size_t tpre = (size_t)((t + 4 < 1024) ? t + 4 : 1023) * 128;
                    wC0 = *(const float4*)(WEg + wegB0 + tpre);
                    wC1 = *(const float4*)(WEg + wegB1 + tpre);
                    *(uint2*)&h0buf[p ^ 1][n][r0] = make_uint2(
                        pk_bf16(fast_tanh(c0[0]), fast_tanh(c0[1])),
                        pk_bf16(fast_tanh(c0[2]), fast_tanh(c0[3])));
                    *(uint2*)&h0buf[p ^ 1][n][r1] = make_uint2(
                        pk_bf16(fast_tanh(c1[0]), fast_tanh(c1[1])),
                        pk_bf16(fast_tanh(c1[2]), fast_tanh(c1[3])));
                }
                bar_lds();
                if ((t & 127) == 127) {
                    asm volatile("s_waitcnt vmcnt(0)" ::: "memory");
                    __syncthreads();
                    if (tid == 0) rel_store(flags + bx, t + 1);
                }
            }
        } else {
            const int w2 = w - 4;
            const int r0 = w2 * 32 + quad * 4;
            const int r1 = r0 + 16;
            short8 a1[2][4], a2[2][4];
#pragma unroll
            for (int r = 0; r < 2; ++r) {
                const size_t mrow = (size_t)(w2 * 32 + r * 16 + n) * 128;
#pragma unroll
                for (int ks = 0; ks < 4; ++ks) {
                    a1[r][ks] = ld_a_bf16(w_ih1 + mrow + ks * 32 + quad * 8);
                    a2[r][ks] = ld_a_bf16(w_hh1 + mrow + ks * 32 + quad * 8);
                }
            }
            f32x4 b1i[2];
#pragma unroll
            for (int r = 0; r < 2; ++r)
#pragma unroll
                for (int j = 0; j < 4; ++j) {
                    int row = w2 * 32 + r * 16 + quad * 4 + j;
                    b1i[r][j] = b_ih1[row] + b_hh1[row];
                }
            *(uint2*)&h1buf[0][n][r0] = make_uint2(0u, 0u);
            *(uint2*)&h1buf[0][n][r1] = make_uint2(0u, 0u);
            unsigned short* outp0 = outs_bf + (size_t)(bbase + n) * 131072 + r0;
            unsigned short* outp1 = outp0 + 16;
            __syncthreads();

            for (int t = 0; t < 1024; ++t) {
                const int p = t & 1;
                const unsigned short* h0p = &h0buf[p][n][quad * 8];
                const unsigned short* h1p = &h1buf[p][n][quad * 8];
                short8 bh0[4], bh1[4];
#pragma unroll
                for (int ks = 0; ks < 4; ++ks) {
                    bh0[ks] = *(const short8*)(h0p + ks * 32);
                    bh1[ks] = *(const short8*)(h1p + ks * 32);
                }
                f32x4 c0 = b1i[0], c1 = b1i[1];
                f32x4 d0 = (f32x4){0.f,0.f,0.f,0.f}, d1 = (f32x4){0.f,0.f,0.f,0.f};
#pragma unroll
                for (int ks = 0; ks < 4; ++ks) {
                    c0 = __builtin_amdgcn_mfma_f32_16x16x32_bf16(a1[0][ks], bh0[ks], c0, 0,0,0);
                    c1 = __builtin_amdgcn_mfma_f32_16x16x32_bf16(a1[1][ks], bh0[ks], c1, 0,0,0);
                    d0 = __builtin_amdgcn_mfma_f32_16x16x32_bf16(a2[0][ks], bh1[ks], d0, 0,0,0);
                    d1 = __builtin_amdgcn_mfma_f32_16x16x32_bf16(a2[1][ks], bh1[ks], d1, 0,0,0);
                }
                uint2 o0 = make_uint2(
                    pk_bf16(fast_tanh(c0[0] + d0[0]), fast_tanh(c0[1] + d0[1])),
                    pk_bf16(fast_tanh(c0[2] + d0[2]), fast_tanh(c0[3] + d0[3])));
                uint2 o1 = make_uint2(
                    pk_bf16(fast_tanh(c1[0] + d1[0]), fast_tanh(c1[1] + d1[1])),
                    pk_bf16(fast_tanh(c1[2] + d1[2]), fast_tanh(c1[3] + d1[3])));
                *(uint2*)&h1buf[p ^ 1][n][r0] = o0;
                *(uint2*)&h1buf[p ^ 1][n][r1] = o1;
                *(uint2*)(outp0 + (size_t)t * 128) = o0;
                *(uint2*)(outp1 + (size_t)t * 128) = o1;
                bar_lds();
                if ((t & 127) == 127) {
                    asm volatile("s_waitcnt vmcnt(0)" ::: "memory");
                    __syncthreads();
                    if (tid == 0) rel_store(flags + bx, t + 1);
                }
            }
        }
        return;
    }

    if (bx < 516) {
        // =================== transpose role ===================
        const int i     = bx - 4;
        const int chunk = i >> 6;          // 0..7  (chunk-major: early first)
        const int b     = i & 63;
        if (tid == 0) acq_wait_ge(flags + (b >> 4), (chunk + 1) * 128);
        __syncthreads();

        typedef unsigned short (*LT)[130];
        LT lt = (LT)smem;                  // [128][130]
        const int t0 = chunk * 128;
        const unsigned int* src =
            (const unsigned int*)(outs_bf + ((size_t)b * 1024 + t0) * 128);
        for (int idx = tid; idx < 8192; idx += 512) {
            int tr = idx >> 6, h2 = idx & 63;
            unsigned int v = src[tr * 64 + h2];
            lt[tr][h2 * 2]     = (unsigned short)(v & 0xffffu);
            lt[tr][h2 * 2 + 1] = (unsigned short)(v >> 16);
        }
        __syncthreads();
        unsigned int* dst = (unsigned int*)(outsT + (size_t)b * 131072);
        for (int idx = tid; idx < 8192; idx += 512) {
            int h = idx >> 6, t2 = idx & 63;
            unsigned int v = (unsigned int)lt[t2 * 2][h] |
                             ((unsigned int)lt[t2 * 2 + 1][h] << 16);
            dst[h * 512 + (t0 >> 1) + t2] = v;
        }
        asm volatile("s_waitcnt vmcnt(0)" ::: "memory");
        __syncthreads();
        if (tid == 0) rel_store(flags + 16 + b * 8 + chunk, 1);
        return;
    }

    // =================== attn + FC role ===================
    {
        const int i  = bx - 516;
        const int qt = i >> 6;             // ascending -> early qt first
        const int b  = i & 63;
        if (tid == 0) {
            for (int c = 0; c <= qt; ++c) acq_wait_ge(flags + 16 + b * 8 + c, 1);
        }
        __syncthreads();

        unsigned short* lK = (unsigned short*)smem;             // [128][128] swz
        unsigned short* lV = (unsigned short*)(smem + 32768);   // [128][128] swz (V^T)
        unsigned short* lP = (unsigned short*)(smem + 65536);   // [8][16][136]
        unsigned short* lPw = lP + w * 2176;
        const float cscale = 0.08838834764831845f;              // 1/sqrt(128)

        const unsigned short* outsB = outs_bf + (size_t)b * 131072;
        const int qrow = qt * 128 + w * 16 + n;                 // this lane's q

        // ---- Phase Q: Q = attn_w @ outs_q + attn_b (per-wave 16 rows) ----
        short8 bo[4];
#pragma unroll
        for (int ks = 0; ks < 4; ++ks)
            bo[ks] = *(const short8*)(outsB + (size_t)qrow * 128 + ks * 32 + quad * 8);
#pragma unroll
        for (int mt = 0; mt < 8; ++mt) {
            short8 aw[4];
#pragma unroll
            for (int ks = 0; ks < 4; ++ks)
                aw[ks] = ld_a_bf16(attn_w + (size_t)(mt * 16 + n) * 128 + ks * 32 + quad * 8);
            f32x4 cq;
#pragma unroll
            for (int r = 0; r < 4; ++r) cq[r] = attn_b[mt * 16 + quad * 4 + r];
#pragma unroll
            for (int ks = 0; ks < 4; ++ks)
                cq = __builtin_amdgcn_mfma_f32_16x16x32_bf16(aw[ks], bo[ks], cq, 0,0,0);
            *(uint2*)&lPw[n * 136 + mt * 16 + quad * 4] =
                make_uint2(pk_bf16(cq[0], cq[1]), pk_bf16(cq[2], cq[3]));
        }
        short8 qf[4];
#pragma unroll
        for (int ks = 0; ks < 4; ++ks)
            qf[ks] = *(const short8*)&lPw[n * 136 + ks * 32 + quad * 8];

        f32x4 accO[8];
#pragma unroll
        for (int dt = 0; dt < 8; ++dt) accO[dt] = (f32x4){0.f, 0.f, 0.f, 0.f};
        float mx = -1e30f, lsum = 0.f;

        for (int kt = 0; kt <= qt; ++kt) {
            __syncthreads();                   // previous iter done with lK/lV
            for (int c = tid; c < 2048; c += 512) {
                int row = c >> 4, k8 = c & 15;
                uint4 vk = *(const uint4*)(outsB + (size_t)(kt * 128 + row) * 128 + k8 * 8);
                *(uint4*)&lK[row * 128 + ((k8 ^ (row & 15)) << 3)] = vk;
                uint4 vv = *(const uint4*)(outsT + ((size_t)b * 128 + row) * 1024 +
                                           kt * 128 + k8 * 8);
                *(uint4*)&lV[row * 128 + ((k8 ^ (row & 15)) << 3)] = vv;
            }
            __syncthreads();
            // ---- S^T = K · Q^T ----
            f32x4 accS[8];
#pragma unroll
            for (int mt = 0; mt < 8; ++mt) {
                short8 af[4];
#pragma unroll
                for (int ks = 0; ks < 4; ++ks) {
                    int r = mt * 16 + n;
                    af[ks] = *(const short8*)&lK[r * 128 + (((ks * 4 + quad) ^ (r & 15)) << 3)];
                }
                f32x4 s = (f32x4){0.f, 0.f, 0.f, 0.f};
#pragma unroll
                for (int ks = 0; ks < 4; ++ks)
                    s = __builtin_amdgcn_mfma_f32_16x16x32_bf16(af[ks], qf[ks], s, 0,0,0);
                accS[mt] = s;
            }
            if (kt == qt) {
                const int ql = w * 16 + n;
#pragma unroll
                for (int mt = 0; mt < 8; ++mt)
#pragma unroll
                    for (int jv = 0; jv < 4; ++jv)
                        if (mt * 16 + quad * 4 + jv > ql) accS[mt][jv] = -1e30f;
            }
            // ---- online softmax ----
            float tmax = accS[0][0];
#pragma unroll
            for (int mt = 0; mt < 8; ++mt)
#pragma unroll
                for (int jv = 0; jv < 4; ++jv) tmax = fmaxf(tmax, accS[mt][jv]);
            tmax = fmaxf(tmax, __shfl_xor(tmax, 16));
            tmax = fmaxf(tmax, __shfl_xor(tmax, 32));
            float nm = fmaxf(mx, tmax);
            float alpha = __expf((mx - nm) * cscale);
            float ss = 0.f;
#pragma unroll
            for (int mt = 0; mt < 8; ++mt)
#pragma unroll
                for (int jv = 0; jv < 4; ++jv) {
                    float p = __expf((accS[mt][jv] - nm) * cscale);
                    accS[mt][jv] = p;
                    ss += p;
                }
            ss += __shfl_xor(ss, 16);
            ss += __shfl_xor(ss, 32);
            lsum = lsum * alpha + ss;
            mx = nm;
            // ---- P^T -> wave-private LDS ----
#pragma unroll
            for (int mt = 0; mt < 8; ++mt)
                *(uint2*)&lPw[n * 136 + mt * 16 + quad * 4] = make_uint2(
                    pk_bf16(accS[mt][0], accS[mt][1]),
                    pk_bf16(accS[mt][2], accS[mt][3]));
#pragma unroll
            for (int dt = 0; dt < 8; ++dt)
#pragma unroll
                for (int jv = 0; jv < 4; ++jv) accO[dt][jv] *= alpha;
            short8 pf[4];
#pragma unroll
            for (int ks = 0; ks < 4; ++ks)
                pf[ks] = *(const short8*)&lPw[n * 136 + ks * 32 + quad * 8];
            // ---- O^T += V^T · P^T ----
#pragma unroll
            for (int dt = 0; dt < 8; ++dt) {
                short8 vf[4];
#pragma unroll
                for (int ks = 0; ks < 4; ++ks) {
                    int d = dt * 16 + n;
                    vf[ks] = *(const short8*)&lV[d * 128 + (((ks * 4 + quad) ^ (d & 15)) << 3)];
                }
#pragma unroll
                for (int ks = 0; ks < 4; ++ks)
                    accO[dt] = __builtin_amdgcn_mfma_f32_16x16x32_bf16(vf[ks], pf[ks], accO[dt], 0,0,0);
            }
        }
        // ---- epilogue: ctx (bf16) -> wave-private LDS ----
        {
            float inv = __builtin_amdgcn_rcpf(lsum);
#pragma unroll
            for (int dt = 0; dt < 8; ++dt)
                *(uint2*)&lPw[n * 136 + dt * 16 + quad * 4] = make_uint2(
                    pk_bf16(accO[dt][0] * inv, accO[dt][1] * inv),
                    pk_bf16(accO[dt][2] * inv, accO[dt][3] * inv));
        }
        // ---- inline FC: logits = [outs|ctx] @ fc_w.T + fc_b ----
        short8 bC[4];
#pragma unroll
        for (int ks = 0; ks < 4; ++ks)
            bC[ks] = *(const short8*)&lPw[n * 136 + ks * 32 + quad * 8];
#pragma unroll
        for (int mt = 0; mt < 4; ++mt) {
            const int vrow = mt * 16 + n;              // A-operand row (v)
            f32x4 acc;
#pragma unroll
            for (int r = 0; r < 4; ++r) {
                int vv = mt * 16 + quad * 4 + r;
                acc[r] = (vv < 55) ? fc_b[vv] : 0.f;
            }
#pragma unroll
            for (int c = 0; c < 8; ++c) {
                short8 hi, lo;
                if (vrow < 55) {
                    ld_fc_hilo(fc_w + (size_t)vrow * 256 + c * 32 + quad * 8, hi, lo);
                } else {
#pragma unroll
                    for (int ii = 0; ii < 8; ++ii) { hi[ii] = 0; lo[ii] = 0; }
                }
                short8 bb = (c < 4) ? bo[c] : bC[c - 4];
                acc = __builtin_amdgcn_mfma_f32_16x16x32_bf16(hi, bb, acc, 0,0,0);
                acc = __builtin_amdgcn_mfma_f32_16x16x32_bf16(lo, bb, acc, 0,0,0);
            }
#pragma unroll
            for (int r = 0; r < 4; ++r) {
                int vv = mt * 16 + quad * 4 + r;
                if (vv < 55)
                    out[((size_t)b * 1024 + qrow) * 55 + vv] = acc[r];
            }
        }
    }
}

// ---------------------------------------------------------------------------
extern "C" void kernel_launch(void* const* d_in, const int* in_sizes, int n_in,
                              void* d_out, int out_size, void* d_ws, size_t ws_size,
                              hipStream_t stream)
{
    const int*   x      = (const int*)d_in[0];
    const float* emb    = (const float*)d_in[1];
    const float* w_ih0  = (const float*)d_in[2];
    const float* b_ih0  = (const float*)d_in[3];
    const float* w_hh0  = (const float*)d_in[4];
    const float* b_hh0  = (const float*)d_in[5];
    const float* w_ih1  = (const float*)d_in[6];
    const float* b_ih1  = (const float*)d_in[7];
    const float* w_hh1  = (const float*)d_in[8];
    const float* b_hh1  = (const float*)d_in[9];
    const float* attn_w = (const float*)d_in[10];
    const float* attn_b = (const float*)d_in[11];
    const float* fc_w   = (const float*)d_in[12];
    const float* fc_b   = (const float*)d_in[13];
    float* out = (float*)d_out;

    char* ws = (char*)d_ws;
    unsigned short* outs_bf = (unsigned short*)(ws);                       // 16 MiB
    unsigned short* outsT   = (unsigned short*)(ws + ((size_t)16 << 20));  // 16 MiB
    float*          WEp     = (float*)         (ws + ((size_t)32 << 20));  // 28 KiB
    int*            flags   = (int*)           (ws + ((size_t)32 << 20) + (64 << 10)); // 2.2 KiB
    float*          WEg     = (float*)         (ws + ((size_t)33 << 20));  // 32 MiB

    k_zero<<<dim3(1), dim3(1024), 0, stream>>>(flags);
    k_we<<<dim3(55), dim3(128), 0, stream>>>(emb, w_ih0, b_ih0, b_hh0, WEp);
    k_weg<<<dim3(32, 64), dim3(256), 0, stream>>>(x, WEp, WEg);
    k_fused<<<dim3(1028), dim3(512), 0, stream>>>(
        WEg, w_hh0, w_ih1, b_ih1, w_hh1, b_hh1, outs_bf, outsT,
        attn_w, attn_b, fc_w, fc_b, out, flags);
}

// Round 3
// 846.174 us; speedup vs baseline: 1.4480x; 1.4480x over previous
//
#include <hip/hip_runtime.h>
#include <hip/hip_bf16.h>
#include <cstdint>
#include <cstddef>

// ---------------------------------------------------------------------------
// RNNAttentionModel: embed -> 2-layer tanh RNN scan (8-wave, wave-specialized)
// FUSED with transpose + (qproj + flash attn + FC) via 4 scan blocks + 252
// persistent worker blocks pulling from a dependency-ordered work queue.
// Grid = 256 blocks exactly (1 block/CU via 100KB LDS) -> everything resident.
// Polls are RELAXED (no invalidate); one acquire load after success.
// B=64 T=1024 E=64 H=128 V=55
// ---------------------------------------------------------------------------

typedef __attribute__((ext_vector_type(8))) short short8;
typedef __attribute__((ext_vector_type(4))) float f32x4;

__device__ __forceinline__ float bf2f(unsigned short u) {
    union { unsigned int i; float f; } c; c.i = ((unsigned int)u) << 16; return c.f;
}
__device__ __forceinline__ unsigned short f2bf(float f) {
    union { float f; unsigned int i; } c; c.f = f;
    unsigned int u = c.i;
    u += 0x7fffu + ((u >> 16) & 1u);   // RNE
    return (unsigned short)(u >> 16);
}
__device__ __forceinline__ unsigned int pk_bf16(float lo, float hi) {
    union { __hip_bfloat162 h2; unsigned int u; } c;
    c.h2 = __float22bfloat162_rn(make_float2(lo, hi));
    return c.u;
}
__device__ __forceinline__ float fast_tanh(float x) {
    float e = __expf(2.0f * x);
    return 1.0f - 2.0f * __builtin_amdgcn_rcpf(e + 1.0f);
}
__device__ __forceinline__ void bar_lds() {
    asm volatile("s_waitcnt lgkmcnt(0)\n\ts_barrier" ::: "memory");
}
__device__ __forceinline__ short8 ld_a_bf16(const float* p) {
    const float4* q = (const float4*)p;
    float4 f0 = q[0], f1 = q[1];
    short8 r;
    r[0]=(short)f2bf(f0.x); r[1]=(short)f2bf(f0.y);
    r[2]=(short)f2bf(f0.z); r[3]=(short)f2bf(f0.w);
    r[4]=(short)f2bf(f1.x); r[5]=(short)f2bf(f1.y);
    r[6]=(short)f2bf(f1.z); r[7]=(short)f2bf(f1.w);
    return r;
}
// split-precision load: hi = bf16(w), lo = bf16(w - hi); hi+lo ~ f32 weight
__device__ __forceinline__ void ld_fc_hilo(const float* p, short8& hi, short8& lo) {
    const float4* q = (const float4*)p;
    float4 f0 = q[0], f1 = q[1];
    float ff[8] = {f0.x, f0.y, f0.z, f0.w, f1.x, f1.y, f1.z, f1.w};
#pragma unroll
    for (int i = 0; i < 8; ++i) {
        unsigned short hb = f2bf(ff[i]);
        hi[i] = (short)hb;
        lo[i] = (short)f2bf(ff[i] - bf2f(hb));
    }
}
// ---- cross-XCD sync helpers ----
__device__ __forceinline__ void rel_store(int* p, int v) {
    __threadfence();   // flush this XCD's L2 (writes reach coherence point)
    __hip_atomic_store(p, v, __ATOMIC_RELEASE, __HIP_MEMORY_SCOPE_AGENT);
}
__device__ __forceinline__ int rlx_load(const int* p) {
    return __hip_atomic_load(p, __ATOMIC_RELAXED, __HIP_MEMORY_SCOPE_AGENT);
}
__device__ __forceinline__ void acq_touch(const int* p) {
    (void)__hip_atomic_load(p, __ATOMIC_ACQUIRE, __HIP_MEMORY_SCOPE_AGENT);
}

// ---------------------------------------------------------------------------
// K0a: WE[v][i] = w_ih0[i,:] . emb[v,:] + b_ih0[i] + b_hh0[i]   (55 x 128)
// ---------------------------------------------------------------------------
__global__ __launch_bounds__(128)
void k_we(const float* __restrict__ emb, const float* __restrict__ w_ih0,
          const float* __restrict__ b_ih0, const float* __restrict__ b_hh0,
          float* __restrict__ WE)
{
    __shared__ float ev[64];
    const int i = threadIdx.x;
    const int v = blockIdx.x;
    if (i < 64) ev[i] = emb[v * 64 + i];
    __syncthreads();
    float s = b_ih0[i] + b_hh0[i];
    const float* wr = w_ih0 + i * 64;
#pragma unroll
    for (int k = 0; k < 64; ++k) s += wr[k] * ev[k];
    WE[v * 128 + i] = s;
}

// ---------------------------------------------------------------------------
// K0b: WEg[b][t][:] = WE[x[b][t]][:]
// ---------------------------------------------------------------------------
__global__ __launch_bounds__(256)
void k_weg(const int* __restrict__ x, const float* __restrict__ WE,
           float* __restrict__ WEg)
{
    __shared__ int xv[32];
    const int tid = threadIdx.x;
    const int b   = blockIdx.y;
    const int t0  = blockIdx.x * 32;
    if (tid < 32) xv[tid] = x[b * 1024 + t0 + tid];
    __syncthreads();
#pragma unroll
    for (int it = 0; it < 4; ++it) {
        int tt = it * 8 + (tid >> 5);
        int c4 = tid & 31;
        float4 v = ((const float4*)(WE + xv[tt] * 128))[c4];
        ((float4*)(WEg + ((size_t)b * 1024 + t0 + tt) * 128))[c4] = v;
    }
}

// ---------------------------------------------------------------------------
// flag zeroing (re-run safe; kernel boundary gives device-wide visibility)
// flags[0..3]=scan progress; flags[16+b*8+c]=transpose chunk done;
// flags[768]=work-queue counter
// ---------------------------------------------------------------------------
__global__ __launch_bounds__(1024)
void k_zero(int* __restrict__ f)
{
    f[threadIdx.x] = 0;
}

// ---------------------------------------------------------------------------
// Fused kernel. blockIdx.x < 4: RNN scan. Else: persistent worker pulling
// items from queue. Item idx in [0,1024): group=idx>>6 (0..15), b=idx&63,
// c=group>>1; even group -> transpose chunk c of b; odd -> attn qt=c of b.
// ---------------------------------------------------------------------------
__global__ __launch_bounds__(512, 1)
void k_fused(const float* __restrict__ WEg,
             const float* __restrict__ w_hh0,
             const float* __restrict__ w_ih1, const float* __restrict__ b_ih1,
             const float* __restrict__ w_hh1, const float* __restrict__ b_hh1,
             unsigned short* __restrict__ outs_bf,
             unsigned short* __restrict__ outsT,
             const float* __restrict__ attn_w, const float* __restrict__ attn_b,
             const float* __restrict__ fc_w, const float* __restrict__ fc_b,
             float* __restrict__ out, int* __restrict__ flags)
{
    __shared__ __align__(16) unsigned char smem[100352];
    __shared__ int sidx;
    const int bx   = blockIdx.x;
    const int tid  = threadIdx.x;
    const int w    = tid >> 6;
    const int lane = tid & 63;
    const int quad = lane >> 4;
    const int n    = lane & 15;

    if (bx < 4) {
        // =================== scan role (verified 8-wave k_scan5) ============
        typedef unsigned short (*HBuf)[16][136];
        HBuf h0buf = (HBuf)(smem);           // [2][16][136]
        HBuf h1buf = (HBuf)(smem + 8704);    // [2][16][136]
        const int bbase = bx * 16;

        if (w < 4) {
            const int r0 = w * 32 + quad * 4;
            const int r1 = r0 + 16;
            short8 a0[2][4];
#pragma unroll
            for (int r = 0; r < 2; ++r) {
                const size_t mrow = (size_t)(w * 32 + r * 16 + n) * 128;
#pragma unroll
                for (int ks = 0; ks < 4; ++ks)
                    a0[r][ks] = ld_a_bf16(w_hh0 + mrow + ks * 32 + quad * 8);
            }
            const size_t wegB0 = (size_t)(bbase + n) * 131072 + r0;
            const size_t wegB1 = wegB0 + 16;
            {
                float4 p0 = *(const float4*)(WEg + wegB0);
                float4 p1 = *(const float4*)(WEg + wegB1);
                *(uint2*)&h0buf[0][n][r0] = make_uint2(
                    pk_bf16(fast_tanh(p0.x), fast_tanh(p0.y)),
                    pk_bf16(fast_tanh(p0.z), fast_tanh(p0.w)));
                *(uint2*)&h0buf[0][n][r1] = make_uint2(
                    pk_bf16(fast_tanh(p1.x), fast_tanh(p1.y)),
                    pk_bf16(fast_tanh(p1.z), fast_tanh(p1.w)));
            }
            float4 wA0 = *(const float4*)(WEg + wegB0 + 128);
            float4 wA1 = *(const float4*)(WEg + wegB1 + 128);
            float4 wB0 = *(const float4*)(WEg + wegB0 + 256);
            float4 wB1 = *(const float4*)(WEg + wegB1 + 256);
            float4 wC0 = *(const float4*)(WEg + wegB0 + 384);
            float4 wC1 = *(const float4*)(WEg + wegB1 + 384);
            __syncthreads();

            for (int t = 0; t < 1024; ++t) {
                const int p = t & 1;
                if (t < 1023) {
                    const unsigned short* h0p = &h0buf[p][n][quad * 8];
                    short8 bh[4];
#pragma unroll
                    for (int ks = 0; ks < 4; ++ks)
                        bh[ks] = *(const short8*)(h0p + ks * 32);
                    f32x4 c0 = (f32x4){wA0.x, wA0.y, wA0.z, wA0.w};
                    f32x4 c1 = (f32x4){wA1.x, wA1.y, wA1.z, wA1.w};
#pragma unroll
                    for (int ks = 0; ks < 4; ++ks) {
                        c0 = __builtin_amdgcn_mfma_f32_16x16x32_bf16(a0[0][ks], bh[ks], c0, 0,0,0);
                        c1 = __builtin_amdgcn_mfma_f32_16x16x32_bf16(a0[1][ks], bh[ks], c1, 0,0,0);
                    }
                    wA0 = wB0; wA1 = wB1; wB0 = wC0; wB1 = wC1;
                    const size_t tpre = (size_t)((t + 4 < 1024) ? t + 4 : 1023) * 128;
                    wC0 = *(const float4*)(WEg + wegB0 + tpre);
                    wC1 = *(const float4*)(WEg + wegB1 + tpre);
                    *(uint2*)&h0buf[p ^ 1][n][r0] = make_uint2(
                        pk_bf16(fast_tanh(c0[0]), fast_tanh(c0[1])),
                        pk_bf16(fast_tanh(c0[2]), fast_tanh(c0[3])));
                    *(uint2*)&h0buf[p ^ 1][n][r1] = make_uint2(
                        pk_bf16(fast_tanh(c1[0]), fast_tanh(c1[1])),
                        pk_bf16(fast_tanh(c1[2]), fast_tanh(c1[3])));
                }
                bar_lds();
                if ((t & 127) == 127) {
                    asm volatile("s_waitcnt vmcnt(0)" ::: "memory");
                    __syncthreads();
                    if (tid == 0) rel_store(flags + bx, t + 1);
                }
            }
        } else {
            const int w2 = w - 4;
            const int r0 = w2 * 32 + quad * 4;
            const int r1 = r0 + 16;
            short8 a1[2][4], a2[2][4];
#pragma unroll
            for (int r = 0; r < 2; ++r) {
                const size_t mrow = (size_t)(w2 * 32 + r * 16 + n) * 128;
#pragma unroll
                for (int ks = 0; ks < 4; ++ks) {
                    a1[r][ks] = ld_a_bf16(w_ih1 + mrow + ks * 32 + quad * 8);
                    a2[r][ks] = ld_a_bf16(w_hh1 + mrow + ks * 32 + quad * 8);
                }
            }
            f32x4 b1i[2];
#pragma unroll
            for (int r = 0; r < 2; ++r)
#pragma unroll
                for (int j = 0; j < 4; ++j) {
                    int row = w2 * 32 + r * 16 + quad * 4 + j;
                    b1i[r][j] = b_ih1[row] + b_hh1[row];
                }
            *(uint2*)&h1buf[0][n][r0] = make_uint2(0u, 0u);
            *(uint2*)&h1buf[0][n][r1] = make_uint2(0u, 0u);
            unsigned short* outp0 = outs_bf + (size_t)(bbase + n) * 131072 + r0;
            unsigned short* outp1 = outp0 + 16;
            __syncthreads();

            for (int t = 0; t < 1024; ++t) {
                const int p = t & 1;
                const unsigned short* h0p = &h0buf[p][n][quad * 8];
                const unsigned short* h1p = &h1buf[p][n][quad * 8];
                short8 bh0[4], bh1[4];
#pragma unroll
                for (int ks = 0; ks < 4; ++ks) {
                    bh0[ks] = *(const short8*)(h0p + ks * 32);
                    bh1[ks] = *(const short8*)(h1p + ks * 32);
                }
                f32x4 c0 = b1i[0], c1 = b1i[1];
                f32x4 d0 = (f32x4){0.f,0.f,0.f,0.f}, d1 = (f32x4){0.f,0.f,0.f,0.f};
#pragma unroll
                for (int ks = 0; ks < 4; ++ks) {
                    c0 = __builtin_amdgcn_mfma_f32_16x16x32_bf16(a1[0][ks], bh0[ks], c0, 0,0,0);
                    c1 = __builtin_amdgcn_mfma_f32_16x16x32_bf16(a1[1][ks], bh0[ks], c1, 0,0,0);
                    d0 = __builtin_amdgcn_mfma_f32_16x16x32_bf16(a2[0][ks], bh1[ks], d0, 0,0,0);
                    d1 = __builtin_amdgcn_mfma_f32_16x16x32_bf16(a2[1][ks], bh1[ks], d1, 0,0,0);
                }
                uint2 o0 = make_uint2(
                    pk_bf16(fast_tanh(c0[0] + d0[0]), fast_tanh(c0[1] + d0[1])),
                    pk_bf16(fast_tanh(c0[2] + d0[2]), fast_tanh(c0[3] + d0[3])));
                uint2 o1 = make_uint2(
                    pk_bf16(fast_tanh(c1[0] + d1[0]), fast_tanh(c1[1] + d1[1])),
                    pk_bf16(fast_tanh(c1[2] + d1[2]), fast_tanh(c1[3] + d1[3])));
                *(uint2*)&h1buf[p ^ 1][n][r0] = o0;
                *(uint2*)&h1buf[p ^ 1][n][r1] = o1;
                *(uint2*)(outp0 + (size_t)t * 128) = o0;
                *(uint2*)(outp1 + (size_t)t * 128) = o1;
                bar_lds();
                if ((t & 127) == 127) {
                    asm volatile("s_waitcnt vmcnt(0)" ::: "memory");
                    __syncthreads();
                    if (tid == 0) rel_store(flags + bx, t + 1);
                }
            }
        }
        return;
    }

    // =================== persistent worker ===================
    int* qcnt = flags + 768;
    const float cscale = 0.08838834764831845f;              // 1/sqrt(128)

    for (;;) {
        __syncthreads();
        if (tid == 0) sidx = atomicAdd(qcnt, 1);
        __syncthreads();
        const int idx = sidx;
        if (idx >= 1024) break;
        const int group = idx >> 6;        // 0..15
        const int b     = idx & 63;
        const int c     = group >> 1;      // chunk / qt

        if (!(group & 1)) {
            // ---------------- transpose chunk c of batch b ----------------
            if (tid == 0) {
                while (rlx_load(flags + (b >> 4)) < (c + 1) * 128)
                    __builtin_amdgcn_s_sleep(100);
            }
            __syncthreads();
            acq_touch(flags + (b >> 4));

            typedef unsigned short (*LT)[130];
            LT lt = (LT)smem;                  // [128][130]
            const int t0 = c * 128;
            const unsigned int* src =
                (const unsigned int*)(outs_bf + ((size_t)b * 1024 + t0) * 128);
            for (int i2 = tid; i2 < 8192; i2 += 512) {
                int tr = i2 >> 6, h2 = i2 & 63;
                unsigned int v = src[tr * 64 + h2];
                lt[tr][h2 * 2]     = (unsigned short)(v & 0xffffu);
                lt[tr][h2 * 2 + 1] = (unsigned short)(v >> 16);
            }
            __syncthreads();
            unsigned int* dst = (unsigned int*)(outsT + (size_t)b * 131072);
            for (int i2 = tid; i2 < 8192; i2 += 512) {
                int h = i2 >> 6, t2 = i2 & 63;
                unsigned int v = (unsigned int)lt[t2 * 2][h] |
                                 ((unsigned int)lt[t2 * 2 + 1][h] << 16);
                dst[h * 512 + (t0 >> 1) + t2] = v;
            }
            asm volatile("s_waitcnt vmcnt(0)" ::: "memory");
            __syncthreads();
            if (tid == 0) rel_store(flags + 16 + b * 8 + c, 1);
            continue;
        }

        // ---------------- attn + FC item: qt=c, batch b ----------------
        {
            const int qt = c;
            if (tid == 0) {
                for (int cc = 0; cc <= qt; ++cc)
                    while (rlx_load(flags + 16 + b * 8 + cc) < 1)
                        __builtin_amdgcn_s_sleep(100);
            }
            __syncthreads();
            acq_touch(flags + 16 + b * 8 + qt);

            unsigned short* lK = (unsigned short*)smem;             // [128][128] swz
            unsigned short* lV = (unsigned short*)(smem + 32768);   // [128][128] swz (V^T)
            unsigned short* lP = (unsigned short*)(smem + 65536);   // [8][16][136]
            unsigned short* lPw = lP + w * 2176;

            const unsigned short* outsB = outs_bf + (size_t)b * 131072;
            const int qrow = qt * 128 + w * 16 + n;                 // this lane's q

            // ---- Phase Q: Q = attn_w @ outs_q + attn_b ----
            short8 bo[4];
#pragma unroll
            for (int ks = 0; ks < 4; ++ks)
                bo[ks] = *(const short8*)(outsB + (size_t)qrow * 128 + ks * 32 + quad * 8);
#pragma unroll
            for (int mt = 0; mt < 8; ++mt) {
                short8 aw[4];
#pragma unroll
                for (int ks = 0; ks < 4; ++ks)
                    aw[ks] = ld_a_bf16(attn_w + (size_t)(mt * 16 + n) * 128 + ks * 32 + quad * 8);
                f32x4 cq;
#pragma unroll
                for (int r = 0; r < 4; ++r) cq[r] = attn_b[mt * 16 + quad * 4 + r];
#pragma unroll
                for (int ks = 0; ks < 4; ++ks)
                    cq = __builtin_amdgcn_mfma_f32_16x16x32_bf16(aw[ks], bo[ks], cq, 0,0,0);
                *(uint2*)&lPw[n * 136 + mt * 16 + quad * 4] =
                    make_uint2(pk_bf16(cq[0], cq[1]), pk_bf16(cq[2], cq[3]));
            }
            short8 qf[4];
#pragma unroll
            for (int ks = 0; ks < 4; ++ks)
                qf[ks] = *(const short8*)&lPw[n * 136 + ks * 32 + quad * 8];

            f32x4 accO[8];
#pragma unroll
            for (int dt = 0; dt < 8; ++dt) accO[dt] = (f32x4){0.f, 0.f, 0.f, 0.f};
            float mx = -1e30f, lsum = 0.f;

            for (int kt = 0; kt <= qt; ++kt) {
                __syncthreads();                   // previous iter done with lK/lV
                for (int cc = tid; cc < 2048; cc += 512) {
                    int row = cc >> 4, k8 = cc & 15;
                    uint4 vk = *(const uint4*)(outsB + (size_t)(kt * 128 + row) * 128 + k8 * 8);
                    *(uint4*)&lK[row * 128 + ((k8 ^ (row & 15)) << 3)] = vk;
                    uint4 vv = *(const uint4*)(outsT + ((size_t)b * 128 + row) * 1024 +
                                               kt * 128 + k8 * 8);
                    *(uint4*)&lV[row * 128 + ((k8 ^ (row & 15)) << 3)] = vv;
                }
                __syncthreads();
                // ---- S^T = K · Q^T ----
                f32x4 accS[8];
#pragma unroll
                for (int mt = 0; mt < 8; ++mt) {
                    short8 af[4];
#pragma unroll
                    for (int ks = 0; ks < 4; ++ks) {
                        int r = mt * 16 + n;
                        af[ks] = *(const short8*)&lK[r * 128 + (((ks * 4 + quad) ^ (r & 15)) << 3)];
                    }
                    f32x4 s = (f32x4){0.f, 0.f, 0.f, 0.f};
#pragma unroll
                    for (int ks = 0; ks < 4; ++ks)
                        s = __builtin_amdgcn_mfma_f32_16x16x32_bf16(af[ks], qf[ks], s, 0,0,0);
                    accS[mt] = s;
                }
                if (kt == qt) {
                    const int ql = w * 16 + n;
#pragma unroll
                    for (int mt = 0; mt < 8; ++mt)
#pragma unroll
                        for (int jv = 0; jv < 4; ++jv)
                            if (mt * 16 + quad * 4 + jv > ql) accS[mt][jv] = -1e30f;
                }
                // ---- online softmax ----
                float tmax = accS[0][0];
#pragma unroll
                for (int mt = 0; mt < 8; ++mt)
#pragma unroll
                    for (int jv = 0; jv < 4; ++jv) tmax = fmaxf(tmax, accS[mt][jv]);
                tmax = fmaxf(tmax, __shfl_xor(tmax, 16));
                tmax = fmaxf(tmax, __shfl_xor(tmax, 32));
                float nm = fmaxf(mx, tmax);
                float alpha = __expf((mx - nm) * cscale);
                float ss = 0.f;
#pragma unroll
                for (int mt = 0; mt < 8; ++mt)
#pragma unroll
                    for (int jv = 0; jv < 4; ++jv) {
                        float p = __expf((accS[mt][jv] - nm) * cscale);
                        accS[mt][jv] = p;
                        ss += p;
                    }
                ss += __shfl_xor(ss, 16);
                ss += __shfl_xor(ss, 32);
                lsum = lsum * alpha + ss;
                mx = nm;
                // ---- P^T -> wave-private LDS ----
#pragma unroll
                for (int mt = 0; mt < 8; ++mt)
                    *(uint2*)&lPw[n * 136 + mt * 16 + quad * 4] = make_uint2(
                        pk_bf16(accS[mt][0], accS[mt][1]),
                        pk_bf16(accS[mt][2], accS[mt][3]));
#pragma unroll
                for (int dt = 0; dt < 8; ++dt)
#pragma unroll
                    for (int jv = 0; jv < 4; ++jv) accO[dt][jv] *= alpha;
                short8 pf[4];
#pragma unroll
                for (int ks = 0; ks < 4; ++ks)
                    pf[ks] = *(const short8*)&lPw[n * 136 + ks * 32 + quad * 8];
                // ---- O^T += V^T · P^T ----
#pragma unroll
                for (int dt = 0; dt < 8; ++dt) {
                    short8 vf[4];
#pragma unroll
                    for (int ks = 0; ks < 4; ++ks) {
                        int d = dt * 16 + n;
                        vf[ks] = *(const short8*)&lV[d * 128 + (((ks * 4 + quad) ^ (d & 15)) << 3)];
                    }
#pragma unroll
                    for (int ks = 0; ks < 4; ++ks)
                        accO[dt] = __builtin_amdgcn_mfma_f32_16x16x32_bf16(vf[ks], pf[ks], accO[dt], 0,0,0);
                }
            }
            // ---- epilogue: ctx (bf16) -> wave-private LDS ----
            {
                float inv = __builtin_amdgcn_rcpf(lsum);
#pragma unroll
                for (int dt = 0; dt < 8; ++dt)
                    *(uint2*)&lPw[n * 136 + dt * 16 + quad * 4] = make_uint2(
                        pk_bf16(accO[dt][0] * inv, accO[dt][1] * inv),
                        pk_bf16(accO[dt][2] * inv, accO[dt][3] * inv));
            }
            // ---- inline FC: logits = [outs|ctx] @ fc_w.T + fc_b ----
            short8 bC[4];
#pragma unroll
            for (int ks = 0; ks < 4; ++ks)
                bC[ks] = *(const short8*)&lPw[n * 136 + ks * 32 + quad * 8];
#pragma unroll
            for (int mt = 0; mt < 4; ++mt) {
                const int vrow = mt * 16 + n;              // A-operand row (v)
                f32x4 acc;
#pragma unroll
                for (int r = 0; r < 4; ++r) {
                    int vv = mt * 16 + quad * 4 + r;
                    acc[r] = (vv < 55) ? fc_b[vv] : 0.f;
                }
#pragma unroll
                for (int cc = 0; cc < 8; ++cc) {
                    short8 hi, lo;
                    if (vrow < 55) {
                        ld_fc_hilo(fc_w + (size_t)vrow * 256 + cc * 32 + quad * 8, hi, lo);
                    } else {
#pragma unroll
                        for (int ii = 0; ii < 8; ++ii) { hi[ii] = 0; lo[ii] = 0; }
                    }
                    short8 bb = (cc < 4) ? bo[cc] : bC[cc - 4];
                    acc = __builtin_amdgcn_mfma_f32_16x16x32_bf16(hi, bb, acc, 0,0,0);
                    acc = __builtin_amdgcn_mfma_f32_16x16x32_bf16(lo, bb, acc, 0,0,0);
                }
#pragma unroll
                for (int r = 0; r < 4; ++r) {
                    int vv = mt * 16 + quad * 4 + r;
                    if (vv < 55)
                        out[((size_t)b * 1024 + qrow) * 55 + vv] = acc[r];
                }
            }
        }
    }
}

// ---------------------------------------------------------------------------
extern "C" void kernel_launch(void* const* d_in, const int* in_sizes, int n_in,
                              void* d_out, int out_size, void* d_ws, size_t ws_size,
                              hipStream_t stream)
{
    const int*   x      = (const int*)d_in[0];
    const float* emb    = (const float*)d_in[1];
    const float* w_ih0  = (const float*)d_in[2];
    const float* b_ih0  = (const float*)d_in[3];
    const float* w_hh0  = (const float*)d_in[4];
    const float* b_hh0  = (const float*)d_in[5];
    const float* w_ih1  = (const float*)d_in[6];
    const float* b_ih1  = (const float*)d_in[7];
    const float* w_hh1  = (const float*)d_in[8];
    const float* b_hh1  = (const float*)d_in[9];
    const float* attn_w = (const float*)d_in[10];
    const float* attn_b = (const float*)d_in[11];
    const float* fc_w   = (const float*)d_in[12];
    const float* fc_b   = (const float*)d_in[13];
    float* out = (float*)d_out;

    char* ws = (char*)d_ws;
    unsigned short* outs_bf = (unsigned short*)(ws);                       // 16 MiB
    unsigned short* outsT   = (unsigned short*)(ws + ((size_t)16 << 20));  // 16 MiB
    float*          WEp     = (float*)         (ws + ((size_t)32 << 20));  // 28 KiB
    int*            flags   = (int*)           (ws + ((size_t)32 << 20) + (64 << 10)); // 4 KiB
    float*          WEg     = (float*)         (ws + ((size_t)33 << 20));  // 32 MiB

    k_zero<<<dim3(1), dim3(1024), 0, stream>>>(flags);
    k_we<<<dim3(55), dim3(128), 0, stream>>>(emb, w_ih0, b_ih0, b_hh0, WEp);
    k_weg<<<dim3(32, 64), dim3(256), 0, stream>>>(x, WEp, WEg);
    k_fused<<<dim3(256), dim3(512), 0, stream>>>(
        WEg, w_hh0, w_ih1, b_ih1, w_hh1, b_hh1, outs_bf, outsT,
        attn_w, attn_b, fc_w, fc_b, out, flags);
}